// Round 1
// baseline (484.780 us; speedup 1.0000x reference)
//
#include <hip/hip_runtime.h>
#include <hip/hip_bf16.h>

#define NN 8192
#define TOTD 128
#define HIDD 64
#define NHEAD 4
#define DHD 32

typedef __attribute__((ext_vector_type(8))) short short8;
typedef __attribute__((ext_vector_type(4))) float f32x4;

__device__ __forceinline__ short f2b(float f) {
  unsigned u = __builtin_bit_cast(unsigned, f);
  u += 0x7fff + ((u >> 16) & 1);   // round-to-nearest-even
  return (short)(u >> 16);
}

// ---------------- K1: xbT[t][n] = bf16(concat(input,hx)[n][t]) ----------------
__global__ void k_build_xT(const float* __restrict__ in, const float* __restrict__ hx,
                           short* __restrict__ xbT) {
  int i = blockIdx.x * 256 + threadIdx.x;      // over 128*8192
  int t = i >> 13;
  int n = i & (NN - 1);
  float v = (t < 64) ? in[n * 64 + t] : hx[n * 64 + (t - 64)];
  xbT[t * NN + n] = f2b(v);
}

// ---------------- K2: q,k projections (q pre-scaled by 1/sqrt(DH)) -----------
__global__ void k_qk(const float* __restrict__ in, const float* __restrict__ hx,
                     const float* __restrict__ Wq, const float* __restrict__ Wk,
                     short* __restrict__ qb, short* __restrict__ kb) {
  __shared__ float xr[TOTD];
  int n = blockIdx.x;
  int tid = threadIdx.x;
  if (tid < TOTD) xr[tid] = (tid < 64) ? in[n * 64 + tid] : hx[n * 64 + (tid - 64)];
  __syncthreads();
  int which = tid >> 7;          // 0 -> q, 1 -> k
  int h = (tid >> 5) & 3;
  int d = tid & 31;
  const float* W = (which ? Wk : Wq) + h * TOTD * DHD + d;
  float acc = 0.f;
#pragma unroll
  for (int t = 0; t < TOTD; ++t) acc += xr[t] * W[t * DHD];
  if (!which) acc *= 0.17677669529663687f;     // 1/sqrt(32)
  (which ? kb : qb)[(h * NN + n) * DHD + d] = f2b(acc);
}

// ---------------- K3: flash pass -> linv + ax = adj @ x ----------------------
// 16 rows per block, 4 waves, 4-way column split (wave w takes 32-col tiles jt%4==w)
__global__ __launch_bounds__(256, 2) void k_attn1(
    const short* __restrict__ qb, const short* __restrict__ kb,
    const short* __restrict__ xbT, float* __restrict__ linv_g,
    float* __restrict__ ax) {
  __shared__ float lpart[4][NHEAD][16];
  __shared__ alignas(16) short Plds[4][16][32];
  __shared__ float axpart[3][16][TOTD];
  const int tid = threadIdx.x;
  const int w = tid >> 6;
  const int l = tid & 63;
  const int row16 = l & 15;
  const int grp = l >> 4;
  const int r0 = blockIdx.x * 16;
  const f32x4 zero4 = {0.f, 0.f, 0.f, 0.f};

  short8 qf[NHEAD];
#pragma unroll
  for (int h = 0; h < NHEAD; ++h)
    qf[h] = *(const short8*)&qb[(h * NN + r0 + row16) * DHD + grp * 8];

  // ---- pass 1: per-head softmax denominators
  float acc[NHEAD][4];
#pragma unroll
  for (int h = 0; h < NHEAD; ++h)
#pragma unroll
    for (int r = 0; r < 4; ++r) acc[h][r] = 0.f;

  for (int jt = w; jt < NN / 32; jt += 4) {
#pragma unroll
    for (int sub = 0; sub < 2; ++sub) {
      int cb = jt * 32 + sub * 16;
#pragma unroll
      for (int h = 0; h < NHEAD; ++h) {
        short8 kf = *(const short8*)&kb[(h * NN + cb + row16) * DHD + grp * 8];
        f32x4 s = __builtin_amdgcn_mfma_f32_16x16x32_bf16(qf[h], kf, zero4, 0, 0, 0);
#pragma unroll
        for (int r = 0; r < 4; ++r) acc[h][r] += __expf(s[r]);
      }
    }
  }
#pragma unroll
  for (int m = 1; m < 16; m <<= 1)
#pragma unroll
    for (int h = 0; h < NHEAD; ++h)
#pragma unroll
      for (int r = 0; r < 4; ++r) acc[h][r] += __shfl_xor(acc[h][r], m, 64);

  if (row16 < NHEAD) {
#pragma unroll
    for (int r = 0; r < 4; ++r) lpart[w][row16][grp * 4 + r] = acc[row16][r];
  }
  __syncthreads();
  float linv[NHEAD][4];
#pragma unroll
  for (int h = 0; h < NHEAD; ++h)
#pragma unroll
    for (int r = 0; r < 4; ++r) {
      int rw = grp * 4 + r;
      linv[h][r] = 1.f / (lpart[0][h][rw] + lpart[1][h][rw] + lpart[2][h][rw] + lpart[3][h][rw]);
    }
  if (tid < 64) {
    int h = tid >> 4, rw = tid & 15;
    linv_g[h * NN + r0 + rw] =
        1.f / (lpart[0][h][rw] + lpart[1][h][rw] + lpart[2][h][rw] + lpart[3][h][rw]);
  }

  // ---- pass 2: P = mean_h softmax_h tile-by-tile, ax += P @ X
  f32x4 axa[8];
#pragma unroll
  for (int cg = 0; cg < 8; ++cg) axa[cg] = zero4;

  for (int jt = w; jt < NN / 32; jt += 4) {
#pragma unroll
    for (int sub = 0; sub < 2; ++sub) {
      int cb = jt * 32 + sub * 16;
      float p[4] = {0.f, 0.f, 0.f, 0.f};
#pragma unroll
      for (int h = 0; h < NHEAD; ++h) {
        short8 kf = *(const short8*)&kb[(h * NN + cb + row16) * DHD + grp * 8];
        f32x4 s = __builtin_amdgcn_mfma_f32_16x16x32_bf16(qf[h], kf, zero4, 0, 0, 0);
#pragma unroll
        for (int r = 0; r < 4; ++r) p[r] += __expf(s[r]) * linv[h][r];
      }
#pragma unroll
      for (int r = 0; r < 4; ++r)
        Plds[w][grp * 4 + r][sub * 16 + row16] = f2b(0.25f * p[r]);
    }
    short8 pa = *(short8*)&Plds[w][row16][grp * 8];
#pragma unroll
    for (int cg = 0; cg < 8; ++cg) {
      short8 xv = *(const short8*)&xbT[(cg * 16 + row16) * NN + jt * 32 + grp * 8];
      axa[cg] = __builtin_amdgcn_mfma_f32_16x16x32_bf16(pa, xv, axa[cg], 0, 0, 0);
    }
  }
  if (w > 0) {
#pragma unroll
    for (int cg = 0; cg < 8; ++cg)
#pragma unroll
      for (int r = 0; r < 4; ++r)
        axpart[w - 1][grp * 4 + r][cg * 16 + row16] = axa[cg][r];
  }
  __syncthreads();
  if (w == 0) {
#pragma unroll
    for (int cg = 0; cg < 8; ++cg)
#pragma unroll
      for (int r = 0; r < 4; ++r) {
        int rw = grp * 4 + r, c = cg * 16 + row16;
        ax[(r0 + rw) * TOTD + c] =
            axa[cg][r] + axpart[0][rw][c] + axpart[1][rw][c] + axpart[2][rw][c];
      }
  }
}

// ---------------- K4: r,z gates; v2T = (r*hx)^T in bf16 ----------------------
__global__ void k_rz(const float* __restrict__ ax, const float* __restrict__ hx,
                     const float* __restrict__ Wr, const float* __restrict__ br,
                     const float* __restrict__ Wz, const float* __restrict__ bz,
                     float* __restrict__ z, short* __restrict__ v2T) {
  __shared__ float axs[2][TOTD];
  int tid = threadIdx.x;
  int rr = tid >> 7;
  int c2 = tid & 127;
  int n = blockIdx.x * 2 + rr;
  axs[rr][c2] = ax[n * TOTD + c2];
  __syncthreads();
  bool isz = c2 >= HIDD;
  int c = c2 & (HIDD - 1);
  const float* W = isz ? Wz : Wr;
  float acc = isz ? bz[c] : br[c];
#pragma unroll
  for (int t = 0; t < TOTD; ++t) acc += axs[rr][t] * W[t * HIDD + c];
  float sg = 1.f / (1.f + __expf(-acc));
  if (isz) z[n * HIDD + c] = sg;
  else     v2T[c * NN + n] = f2b(sg * hx[n * HIDD + c]);
}

// ---------------- K5: a2 = adj @ (r*hx) with stored linv, + GRU epilogue -----
__global__ __launch_bounds__(256, 2) void k_attn2(
    const short* __restrict__ qb, const short* __restrict__ kb,
    const short* __restrict__ v2T, const float* __restrict__ linv_g,
    const float* __restrict__ ax, const float* __restrict__ hx,
    const float* __restrict__ Wh, const float* __restrict__ bh,
    const float* __restrict__ z, float* __restrict__ out) {
  __shared__ alignas(16) short Plds[4][16][32];
  __shared__ float a2part[3][16][HIDD];
  __shared__ float a2s[16][HIDD];
  __shared__ float Whs[TOTD * HIDD];
  const int tid = threadIdx.x;
  const int w = tid >> 6;
  const int l = tid & 63;
  const int row16 = l & 15;
  const int grp = l >> 4;
  const int r0 = blockIdx.x * 16;
  const f32x4 zero4 = {0.f, 0.f, 0.f, 0.f};

  for (int i = tid; i < TOTD * HIDD; i += 256) Whs[i] = Wh[i];

  short8 qf[NHEAD];
#pragma unroll
  for (int h = 0; h < NHEAD; ++h)
    qf[h] = *(const short8*)&qb[(h * NN + r0 + row16) * DHD + grp * 8];
  float linv[NHEAD][4];
#pragma unroll
  for (int h = 0; h < NHEAD; ++h)
#pragma unroll
    for (int r = 0; r < 4; ++r) linv[h][r] = linv_g[h * NN + r0 + grp * 4 + r];

  f32x4 a2a[4];
#pragma unroll
  for (int cg = 0; cg < 4; ++cg) a2a[cg] = zero4;

  for (int jt = w; jt < NN / 32; jt += 4) {
#pragma unroll
    for (int sub = 0; sub < 2; ++sub) {
      int cb = jt * 32 + sub * 16;
      float p[4] = {0.f, 0.f, 0.f, 0.f};
#pragma unroll
      for (int h = 0; h < NHEAD; ++h) {
        short8 kf = *(const short8*)&kb[(h * NN + cb + row16) * DHD + grp * 8];
        f32x4 s = __builtin_amdgcn_mfma_f32_16x16x32_bf16(qf[h], kf, zero4, 0, 0, 0);
#pragma unroll
        for (int r = 0; r < 4; ++r) p[r] += __expf(s[r]) * linv[h][r];
      }
#pragma unroll
      for (int r = 0; r < 4; ++r)
        Plds[w][grp * 4 + r][sub * 16 + row16] = f2b(0.25f * p[r]);
    }
    short8 pa = *(short8*)&Plds[w][row16][grp * 8];
#pragma unroll
    for (int cg = 0; cg < 4; ++cg) {
      short8 vv = *(const short8*)&v2T[(cg * 16 + row16) * NN + jt * 32 + grp * 8];
      a2a[cg] = __builtin_amdgcn_mfma_f32_16x16x32_bf16(pa, vv, a2a[cg], 0, 0, 0);
    }
  }
  if (w > 0) {
#pragma unroll
    for (int cg = 0; cg < 4; ++cg)
#pragma unroll
      for (int r = 0; r < 4; ++r)
        a2part[w - 1][grp * 4 + r][cg * 16 + row16] = a2a[cg][r];
  }
  __syncthreads();
  if (w == 0) {
#pragma unroll
    for (int cg = 0; cg < 4; ++cg)
#pragma unroll
      for (int r = 0; r < 4; ++r) {
        int rw = grp * 4 + r, c = cg * 16 + row16;
        a2s[rw][c] = a2a[cg][r] + a2part[0][rw][c] + a2part[1][rw][c] + a2part[2][rw][c];
      }
  }
  __syncthreads();
  // epilogue: h = tanh([ax[:, :64] | a2] @ Wh + bh); out = z*hx + (1-z)*h
  for (int o = tid; o < 16 * HIDD; o += 256) {
    int rw = o >> 6, c = o & 63;
    const float* axrow = &ax[(r0 + rw) * TOTD];
    float acc = bh[c];
#pragma unroll
    for (int t = 0; t < 64; ++t) acc += axrow[t] * Whs[t * HIDD + c];
#pragma unroll
    for (int t = 0; t < 64; ++t) acc += a2s[rw][t] * Whs[(64 + t) * HIDD + c];
    float hval = tanhf(acc);
    int gi = (r0 + rw) * HIDD + c;
    float zz = z[gi];
    out[gi] = zz * hx[gi] + (1.f - zz) * hval;
  }
}

extern "C" void kernel_launch(void* const* d_in, const int* in_sizes, int n_in,
                              void* d_out, int out_size, void* d_ws, size_t ws_size,
                              hipStream_t stream) {
  const float* in = (const float*)d_in[0];
  const float* hx = (const float*)d_in[1];
  const float* Wq = (const float*)d_in[2];
  const float* Wk = (const float*)d_in[3];
  const float* Wr = (const float*)d_in[4];
  const float* br = (const float*)d_in[5];
  const float* Wz = (const float*)d_in[6];
  const float* bz = (const float*)d_in[7];
  const float* Wh = (const float*)d_in[8];
  const float* bh = (const float*)d_in[9];

  char* ws = (char*)d_ws;
  short* qb   = (short*)(ws + (0u << 20));    // 2 MB
  short* kb   = (short*)(ws + (2u << 20));    // 2 MB
  short* xbT  = (short*)(ws + (4u << 20));    // 2 MB
  float* linv = (float*)(ws + (6u << 20));    // 128 KB
  float* ax   = (float*)(ws + (7u << 20));    // 4 MB
  float* z    = (float*)(ws + (11u << 20));   // 2 MB
  short* v2T  = (short*)(ws + (13u << 20));   // 1 MB
  float* out  = (float*)d_out;

  k_build_xT<<<dim3((NN * TOTD) / 256), dim3(256), 0, stream>>>(in, hx, xbT);
  k_qk<<<dim3(NN), dim3(256), 0, stream>>>(in, hx, Wq, Wk, qb, kb);
  k_attn1<<<dim3(NN / 16), dim3(256), 0, stream>>>(qb, kb, xbT, linv, ax);
  k_rz<<<dim3(NN / 2), dim3(256), 0, stream>>>(ax, hx, Wr, br, Wz, bz, z, v2T);
  k_attn2<<<dim3(NN / 16), dim3(256), 0, stream>>>(qb, kb, v2T, linv, ax, hx, Wh, bh, z, out);
}

// Round 2
// 471.336 us; speedup vs baseline: 1.0285x; 1.0285x over previous
//
#include <hip/hip_runtime.h>
#include <hip/hip_bf16.h>

#define NN 8192
#define TOTD 128
#define HIDD 64
#define NHEAD 4
#define DHD 32

typedef __attribute__((ext_vector_type(8))) short short8;
typedef __attribute__((ext_vector_type(4))) float f32x4;

__device__ __forceinline__ short f2b(float f) {
  unsigned u = __builtin_bit_cast(unsigned, f);
  u += 0x7fff + ((u >> 16) & 1);   // round-to-nearest-even
  return (short)(u >> 16);
}

// ---------------- K1: xbT[t][n] = bf16(concat(input,hx)[n][t]) ----------------
__global__ void k_build_xT(const float* __restrict__ in, const float* __restrict__ hx,
                           short* __restrict__ xbT) {
  int i = blockIdx.x * 256 + threadIdx.x;      // over 128*8192
  int t = i >> 13;
  int n = i & (NN - 1);
  float v = (t < 64) ? in[n * 64 + t] : hx[n * 64 + (t - 64)];
  xbT[t * NN + n] = f2b(v);
}

// ---------------- K2: q,k projections (q pre-scaled by 1/sqrt(DH)) -----------
__global__ void k_qk(const float* __restrict__ in, const float* __restrict__ hx,
                     const float* __restrict__ Wq, const float* __restrict__ Wk,
                     short* __restrict__ qb, short* __restrict__ kb) {
  __shared__ float xr[TOTD];
  int n = blockIdx.x;
  int tid = threadIdx.x;
  if (tid < TOTD) xr[tid] = (tid < 64) ? in[n * 64 + tid] : hx[n * 64 + (tid - 64)];
  __syncthreads();
  int which = tid >> 7;          // 0 -> q, 1 -> k
  int h = (tid >> 5) & 3;
  int d = tid & 31;
  const float* W = (which ? Wk : Wq) + h * TOTD * DHD + d;
  float acc = 0.f;
#pragma unroll
  for (int t = 0; t < TOTD; ++t) acc += xr[t] * W[t * DHD];
  if (!which) acc *= 0.17677669529663687f;     // 1/sqrt(32)
  (which ? kb : qb)[(h * NN + n) * DHD + d] = f2b(acc);
}

// ---------------- K3a: partial softmax denominators (4-way column split) -----
__global__ __launch_bounds__(256, 4) void k_denom(
    const short* __restrict__ qb, const short* __restrict__ kb,
    float* __restrict__ lpart_g) {
  __shared__ float lpart[4][NHEAD][16];
  const int tid = threadIdx.x;
  const int w = tid >> 6;
  const int l = tid & 63;
  const int row16 = l & 15;
  const int grp = l >> 4;
  const int r0 = blockIdx.x * 16;
  const int colq = blockIdx.y;
  const f32x4 zero4 = {0.f, 0.f, 0.f, 0.f};

  short8 qf[NHEAD];
#pragma unroll
  for (int h = 0; h < NHEAD; ++h)
    qf[h] = *(const short8*)&qb[(h * NN + r0 + row16) * DHD + grp * 8];

  float acc[NHEAD][4];
#pragma unroll
  for (int h = 0; h < NHEAD; ++h)
#pragma unroll
    for (int r = 0; r < 4; ++r) acc[h][r] = 0.f;

  for (int i = 0; i < 16; ++i) {
    int jt = colq * 64 + w + i * 4;
#pragma unroll
    for (int sub = 0; sub < 2; ++sub) {
      int cb = jt * 32 + sub * 16;
#pragma unroll
      for (int h = 0; h < NHEAD; ++h) {
        short8 kf = *(const short8*)&kb[(h * NN + cb + row16) * DHD + grp * 8];
        f32x4 s = __builtin_amdgcn_mfma_f32_16x16x32_bf16(qf[h], kf, zero4, 0, 0, 0);
#pragma unroll
        for (int r = 0; r < 4; ++r) acc[h][r] += __expf(s[r]);
      }
    }
  }
#pragma unroll
  for (int m = 1; m < 16; m <<= 1)
#pragma unroll
    for (int h = 0; h < NHEAD; ++h)
#pragma unroll
      for (int r = 0; r < 4; ++r) acc[h][r] += __shfl_xor(acc[h][r], m, 64);

  if (row16 < NHEAD) {
#pragma unroll
    for (int r = 0; r < 4; ++r) lpart[w][row16][grp * 4 + r] = acc[row16][r];
  }
  __syncthreads();
  if (tid < 64) {
    int h = tid >> 4, rw = tid & 15;
    lpart_g[(colq * NHEAD + h) * NN + r0 + rw] =
        lpart[0][h][rw] + lpart[1][h][rw] + lpart[2][h][rw] + lpart[3][h][rw];
  }
}

// ---------------- K3b: linv = 1 / sum of 4 partials ---------------------------
__global__ void k_linv(const float* __restrict__ lpart_g, float* __restrict__ linv_g) {
  int i = blockIdx.x * 256 + threadIdx.x;      // over NHEAD*NN
  float s = lpart_g[i] + lpart_g[NHEAD * NN + i] + lpart_g[2 * NHEAD * NN + i] +
            lpart_g[3 * NHEAD * NN + i];
  linv_g[i] = 1.f / s;
}

// ---------------- K3c: partial ax = (adj @ x) per column quarter -------------
__global__ __launch_bounds__(256, 4) void k_pv1(
    const short* __restrict__ qb, const short* __restrict__ kb,
    const short* __restrict__ xbT, const float* __restrict__ linv_g,
    float* __restrict__ axq) {
  __shared__ alignas(16) short Plds[4][16][32];
  __shared__ float ax_s[16][TOTD];
  const int tid = threadIdx.x;
  const int w = tid >> 6;
  const int l = tid & 63;
  const int row16 = l & 15;
  const int grp = l >> 4;
  const int r0 = blockIdx.x * 16;
  const int colq = blockIdx.y;
  const f32x4 zero4 = {0.f, 0.f, 0.f, 0.f};

  for (int i = tid; i < 16 * TOTD; i += 256) (&ax_s[0][0])[i] = 0.f;

  short8 qf[NHEAD];
#pragma unroll
  for (int h = 0; h < NHEAD; ++h)
    qf[h] = *(const short8*)&qb[(h * NN + r0 + row16) * DHD + grp * 8];
  float linv[NHEAD][4];
#pragma unroll
  for (int h = 0; h < NHEAD; ++h)
#pragma unroll
    for (int r = 0; r < 4; ++r) linv[h][r] = linv_g[h * NN + r0 + grp * 4 + r];

  f32x4 axa[8];
#pragma unroll
  for (int cg = 0; cg < 8; ++cg) axa[cg] = zero4;

  for (int i = 0; i < 16; ++i) {
    int jt = colq * 64 + w + i * 4;
#pragma unroll
    for (int sub = 0; sub < 2; ++sub) {
      int cb = jt * 32 + sub * 16;
      float p[4] = {0.f, 0.f, 0.f, 0.f};
#pragma unroll
      for (int h = 0; h < NHEAD; ++h) {
        short8 kf = *(const short8*)&kb[(h * NN + cb + row16) * DHD + grp * 8];
        f32x4 s = __builtin_amdgcn_mfma_f32_16x16x32_bf16(qf[h], kf, zero4, 0, 0, 0);
#pragma unroll
        for (int r = 0; r < 4; ++r) p[r] += __expf(s[r]) * linv[h][r];
      }
#pragma unroll
      for (int r = 0; r < 4; ++r)
        Plds[w][grp * 4 + r][sub * 16 + row16] = f2b(0.25f * p[r]);
    }
    short8 pa = *(short8*)&Plds[w][row16][grp * 8];
#pragma unroll
    for (int cg = 0; cg < 8; ++cg) {
      short8 xv = *(const short8*)&xbT[(cg * 16 + row16) * NN + jt * 32 + grp * 8];
      axa[cg] = __builtin_amdgcn_mfma_f32_16x16x32_bf16(pa, xv, axa[cg], 0, 0, 0);
    }
  }
  __syncthreads();
#pragma unroll
  for (int ww = 0; ww < 4; ++ww) {
    if (w == ww) {
#pragma unroll
      for (int cg = 0; cg < 8; ++cg)
#pragma unroll
        for (int r = 0; r < 4; ++r)
          ax_s[grp * 4 + r][cg * 16 + row16] += axa[cg][r];
    }
    __syncthreads();
  }
  for (int i = tid; i < 16 * TOTD; i += 256)
    axq[colq * (NN * TOTD) + (r0 + (i >> 7)) * TOTD + (i & 127)] = (&ax_s[0][0])[i];
}

// ---------------- K4: ax reduce + r,z gates; v2T = (r*hx)^T ------------------
__global__ void k_rz(const float* __restrict__ axq, const float* __restrict__ hx,
                     const float* __restrict__ Wr, const float* __restrict__ br,
                     const float* __restrict__ Wz, const float* __restrict__ bz,
                     float* __restrict__ ax, float* __restrict__ z,
                     short* __restrict__ v2T) {
  __shared__ float axs[2][TOTD];
  int tid = threadIdx.x;
  int rr = tid >> 7;
  int c2 = tid & 127;
  int n = blockIdx.x * 2 + rr;
  float s = axq[n * TOTD + c2] + axq[NN * TOTD + n * TOTD + c2] +
            axq[2 * NN * TOTD + n * TOTD + c2] + axq[3 * NN * TOTD + n * TOTD + c2];
  axs[rr][c2] = s;
  ax[n * TOTD + c2] = s;
  __syncthreads();
  bool isz = c2 >= HIDD;
  int c = c2 & (HIDD - 1);
  const float* W = isz ? Wz : Wr;
  float acc = isz ? bz[c] : br[c];
#pragma unroll
  for (int t = 0; t < TOTD; ++t) acc += axs[rr][t] * W[t * HIDD + c];
  float sg = 1.f / (1.f + __expf(-acc));
  if (isz) z[n * HIDD + c] = sg;
  else     v2T[c * NN + n] = f2b(sg * hx[n * HIDD + c]);
}

// ---------------- K5: partial a2 = (adj @ (r*hx)) per column quarter ---------
__global__ __launch_bounds__(256, 4) void k_pv2(
    const short* __restrict__ qb, const short* __restrict__ kb,
    const short* __restrict__ v2T, const float* __restrict__ linv_g,
    float* __restrict__ a2q) {
  __shared__ alignas(16) short Plds[4][16][32];
  __shared__ float a2_s[16][HIDD];
  const int tid = threadIdx.x;
  const int w = tid >> 6;
  const int l = tid & 63;
  const int row16 = l & 15;
  const int grp = l >> 4;
  const int r0 = blockIdx.x * 16;
  const int colq = blockIdx.y;
  const f32x4 zero4 = {0.f, 0.f, 0.f, 0.f};

  for (int i = tid; i < 16 * HIDD; i += 256) (&a2_s[0][0])[i] = 0.f;

  short8 qf[NHEAD];
#pragma unroll
  for (int h = 0; h < NHEAD; ++h)
    qf[h] = *(const short8*)&qb[(h * NN + r0 + row16) * DHD + grp * 8];
  float linv[NHEAD][4];
#pragma unroll
  for (int h = 0; h < NHEAD; ++h)
#pragma unroll
    for (int r = 0; r < 4; ++r) linv[h][r] = linv_g[h * NN + r0 + grp * 4 + r];

  f32x4 a2a[4];
#pragma unroll
  for (int cg = 0; cg < 4; ++cg) a2a[cg] = zero4;

  for (int i = 0; i < 16; ++i) {
    int jt = colq * 64 + w + i * 4;
#pragma unroll
    for (int sub = 0; sub < 2; ++sub) {
      int cb = jt * 32 + sub * 16;
      float p[4] = {0.f, 0.f, 0.f, 0.f};
#pragma unroll
      for (int h = 0; h < NHEAD; ++h) {
        short8 kf = *(const short8*)&kb[(h * NN + cb + row16) * DHD + grp * 8];
        f32x4 s = __builtin_amdgcn_mfma_f32_16x16x32_bf16(qf[h], kf, zero4, 0, 0, 0);
#pragma unroll
        for (int r = 0; r < 4; ++r) p[r] += __expf(s[r]) * linv[h][r];
      }
#pragma unroll
      for (int r = 0; r < 4; ++r)
        Plds[w][grp * 4 + r][sub * 16 + row16] = f2b(0.25f * p[r]);
    }
    short8 pa = *(short8*)&Plds[w][row16][grp * 8];
#pragma unroll
    for (int cg = 0; cg < 4; ++cg) {
      short8 vv = *(const short8*)&v2T[(cg * 16 + row16) * NN + jt * 32 + grp * 8];
      a2a[cg] = __builtin_amdgcn_mfma_f32_16x16x32_bf16(pa, vv, a2a[cg], 0, 0, 0);
    }
  }
  __syncthreads();
#pragma unroll
  for (int ww = 0; ww < 4; ++ww) {
    if (w == ww) {
#pragma unroll
      for (int cg = 0; cg < 4; ++cg)
#pragma unroll
        for (int r = 0; r < 4; ++r)
          a2_s[grp * 4 + r][cg * 16 + row16] += a2a[cg][r];
    }
    __syncthreads();
  }
  for (int i = tid; i < 16 * HIDD; i += 256)
    a2q[colq * (NN * HIDD) + (r0 + (i >> 6)) * HIDD + (i & 63)] = (&a2_s[0][0])[i];
}

// ---------------- K6: a2 reduce + GRU epilogue -------------------------------
__global__ __launch_bounds__(256) void k_final(
    const float* __restrict__ a2q, const float* __restrict__ ax,
    const float* __restrict__ hx, const float* __restrict__ Wh,
    const float* __restrict__ bh, const float* __restrict__ z,
    float* __restrict__ out) {
  __shared__ float Whs[TOTD * HIDD];
  __shared__ float a2s[16][HIDD];
  const int tid = threadIdx.x;
  const int r0 = blockIdx.x * 16;

  for (int i = tid; i < TOTD * HIDD; i += 256) Whs[i] = Wh[i];
  for (int i = tid; i < 16 * HIDD; i += 256) {
    int rw = i >> 6, c = i & 63;
    int gi = (r0 + rw) * HIDD + c;
    a2s[rw][c] = a2q[gi] + a2q[NN * HIDD + gi] + a2q[2 * NN * HIDD + gi] +
                 a2q[3 * NN * HIDD + gi];
  }
  __syncthreads();
  for (int o = tid; o < 16 * HIDD; o += 256) {
    int rw = o >> 6, c = o & 63;
    const float* axrow = &ax[(r0 + rw) * TOTD];
    float acc = bh[c];
#pragma unroll
    for (int t = 0; t < 64; ++t) acc += axrow[t] * Whs[t * HIDD + c];
#pragma unroll
    for (int t = 0; t < 64; ++t) acc += a2s[rw][t] * Whs[(64 + t) * HIDD + c];
    float hval = tanhf(acc);
    int gi = (r0 + rw) * HIDD + c;
    float zz = z[gi];
    out[gi] = zz * hx[gi] + (1.f - zz) * hval;
  }
}

extern "C" void kernel_launch(void* const* d_in, const int* in_sizes, int n_in,
                              void* d_out, int out_size, void* d_ws, size_t ws_size,
                              hipStream_t stream) {
  const float* in = (const float*)d_in[0];
  const float* hx = (const float*)d_in[1];
  const float* Wq = (const float*)d_in[2];
  const float* Wk = (const float*)d_in[3];
  const float* Wr = (const float*)d_in[4];
  const float* br = (const float*)d_in[5];
  const float* Wz = (const float*)d_in[6];
  const float* bz = (const float*)d_in[7];
  const float* Wh = (const float*)d_in[8];
  const float* bh = (const float*)d_in[9];

  char* ws = (char*)d_ws;
  short* qb    = (short*)(ws + (0ull << 20));    // 2 MB
  short* kb    = (short*)(ws + (2ull << 20));    // 2 MB
  short* xbT   = (short*)(ws + (4ull << 20));    // 2 MB
  float* linv  = (float*)(ws + (6ull << 20));    // 128 KB
  float* lpart = (float*)(ws + (6ull * 1048576 + 262144));  // 512 KB
  float* ax    = (float*)(ws + (7ull << 20));    // 4 MB
  float* z     = (float*)(ws + (11ull << 20));   // 2 MB
  short* v2T   = (short*)(ws + (13ull << 20));   // 1 MB
  float* axq   = (float*)(ws + (16ull << 20));   // 16 MB (4 quarters)
  float* a2q   = (float*)(ws + (32ull << 20));   // 8 MB (4 quarters)
  float* out   = (float*)d_out;

  k_build_xT<<<dim3((NN * TOTD) / 256), dim3(256), 0, stream>>>(in, hx, xbT);
  k_qk<<<dim3(NN), dim3(256), 0, stream>>>(in, hx, Wq, Wk, qb, kb);
  k_denom<<<dim3(NN / 16, 4), dim3(256), 0, stream>>>(qb, kb, lpart);
  k_linv<<<dim3((NHEAD * NN) / 256), dim3(256), 0, stream>>>(lpart, linv);
  k_pv1<<<dim3(NN / 16, 4), dim3(256), 0, stream>>>(qb, kb, xbT, linv, axq);
  k_rz<<<dim3(NN / 2), dim3(256), 0, stream>>>(axq, hx, Wr, br, Wz, bz, ax, z, v2T);
  k_pv2<<<dim3(NN / 16, 4), dim3(256), 0, stream>>>(qb, kb, v2T, linv, a2q);
  k_final<<<dim3(NN / 16), dim3(256), 0, stream>>>(a2q, ax, hx, Wh, bh, z, out);
}

// Round 3
// 221.468 us; speedup vs baseline: 2.1889x; 2.1282x over previous
//
#include <hip/hip_runtime.h>
#include <hip/hip_bf16.h>

#define NN 8192
#define TOTD 128
#define HIDD 64
#define NHEAD 4
#define DHD 32
#define NCQ 8                 // column splits for attention kernels
#define JPB (NN / 32 / NCQ)   // 32 column-tiles (jt) per block

typedef __attribute__((ext_vector_type(8))) short short8;
typedef __attribute__((ext_vector_type(4))) float f32x4;

__device__ __forceinline__ short f2b(float f) {
  unsigned u = __builtin_bit_cast(unsigned, f);
  u += 0x7fff + ((u >> 16) & 1);   // round-to-nearest-even
  return (short)(u >> 16);
}

// async global->LDS, 16B per lane; lds base must be wave-uniform (dest = base + lane*16)
__device__ __forceinline__ void gl_lds16(const short* g, short* l) {
  __builtin_amdgcn_global_load_lds(
      (const __attribute__((address_space(1))) void*)g,
      (__attribute__((address_space(3))) void*)l, 16, 0, 0);
}

// ---------------- K1: xb fragments: xb[jt][cg][lane][8] --------------------
// xb_frag(jt,cg,l,e) = x[jt*32 + (l>>4)*8 + e][cg*16 + (l&15)]   (PV B-operand)
__global__ void k_build_xfrag(const float* __restrict__ in, const float* __restrict__ hx,
                              short* __restrict__ xb) {
  int i = blockIdx.x * 256 + threadIdx.x;   // over NN*TOTD, t-fastest
  int n = i >> 7;
  int t = i & 127;
  float v = (t < 64) ? in[n * 64 + t] : hx[n * 64 + (t - 64)];
  int jt = n >> 5, kk = n & 31, cg = t >> 4;
  int l = ((kk >> 3) << 4) | (t & 15);
  xb[(((size_t)jt * 8 + cg) << 9) + (l << 3) + (kk & 7)] = f2b(v);
}

// ---------------- K2: q,k projections into fragment layouts ------------------
// qb[rtile][h][lane][8]: A-frag; kb[jt][h][sub][lane][8]: B-frag
__global__ void k_qk(const float* __restrict__ in, const float* __restrict__ hx,
                     const float* __restrict__ Wq, const float* __restrict__ Wk,
                     short* __restrict__ qb, short* __restrict__ kb) {
  __shared__ float xr[TOTD];
  int n = blockIdx.x;
  int tid = threadIdx.x;
  if (tid < TOTD) xr[tid] = (tid < 64) ? in[n * 64 + tid] : hx[n * 64 + (tid - 64)];
  __syncthreads();
  int which = tid >> 7;          // 0 -> q, 1 -> k
  int h = (tid >> 5) & 3;
  int d = tid & 31;
  const float* W = (which ? Wk : Wq) + h * TOTD * DHD + d;
  float acc = 0.f;
#pragma unroll
  for (int t = 0; t < TOTD; ++t) acc += xr[t] * W[t * DHD];
  int l = ((d >> 3) << 4) | (n & 15);
  if (!which) {
    acc *= 0.17677669529663687f;   // 1/sqrt(32)
    qb[(((size_t)(n >> 4) * 4 + h) << 9) + (l << 3) + (d & 7)] = f2b(acc);
  } else {
    kb[((((size_t)(n >> 5) * 4 + h) * 2 + ((n >> 4) & 1)) << 9) + (l << 3) + (d & 7)] = f2b(acc);
  }
}

// ---------------- K3a: partial softmax denominators --------------------------
__global__ __launch_bounds__(256, 4) void k_denom(
    const short* __restrict__ qb, const short* __restrict__ kb,
    float* __restrict__ lpart_g) {
  __shared__ short kbuf[2][8 * 512];
  const int tid = threadIdx.x;
  const int w = tid >> 6, l = tid & 63;
  const int row16 = l & 15, grp = l >> 4;
  const int r0 = blockIdx.x * 64 + w * 16;
  const int rtile = blockIdx.x * 4 + w;
  const int jt0 = blockIdx.y * JPB;
  const f32x4 zero4 = {0.f, 0.f, 0.f, 0.f};

  short8 qf[NHEAD];
#pragma unroll
  for (int h = 0; h < NHEAD; ++h)
    qf[h] = *(const short8*)&qb[(((size_t)rtile * 4 + h) << 9) + l * 8];

  float acc[NHEAD][4];
#pragma unroll
  for (int h = 0; h < NHEAD; ++h)
#pragma unroll
    for (int r = 0; r < 4; ++r) acc[h][r] = 0.f;

  for (int c = w; c < 8; c += 4)
    gl_lds16(kb + (((size_t)jt0 * 8 + c) << 9) + l * 8, &kbuf[0][c * 512]);
  __syncthreads();

  for (int j = 0; j < JPB; ++j) {
    int b = j & 1;
    if (j + 1 < JPB)
      for (int c = w; c < 8; c += 4)
        gl_lds16(kb + (((size_t)(jt0 + j + 1) * 8 + c) << 9) + l * 8, &kbuf[b ^ 1][c * 512]);
#pragma unroll
    for (int hs = 0; hs < 8; ++hs) {
      short8 kf = *(const short8*)&kbuf[b][hs * 512 + l * 8];
      f32x4 s = __builtin_amdgcn_mfma_f32_16x16x32_bf16(qf[hs >> 1], kf, zero4, 0, 0, 0);
#pragma unroll
      for (int r = 0; r < 4; ++r) acc[hs >> 1][r] += __expf(s[r]);
    }
    __syncthreads();
  }
#pragma unroll
  for (int m = 1; m < 16; m <<= 1)
#pragma unroll
    for (int h = 0; h < NHEAD; ++h)
#pragma unroll
      for (int r = 0; r < 4; ++r) acc[h][r] += __shfl_xor(acc[h][r], m, 64);

  if (row16 == 0) {
#pragma unroll
    for (int h = 0; h < NHEAD; ++h)
#pragma unroll
      for (int r = 0; r < 4; ++r)
        lpart_g[((size_t)blockIdx.y * NHEAD + h) * NN + r0 + grp * 4 + r] = acc[h][r];
  }
}

// ---------------- K3b: linv = 1 / sum of NCQ partials ------------------------
__global__ void k_linv(const float* __restrict__ lpart_g, float* __restrict__ linv_g) {
  int i = blockIdx.x * 256 + threadIdx.x;      // over NHEAD*NN
  float s = 0.f;
#pragma unroll
  for (int q = 0; q < NCQ; ++q) s += lpart_g[(size_t)q * NHEAD * NN + i];
  linv_g[i] = 1.f / s;
}

// ---------------- K3c: P formation + ax partials (+ optional P store) --------
__global__ __launch_bounds__(256, 4) void k_pv1(
    const short* __restrict__ qb, const short* __restrict__ kb,
    const short* __restrict__ xb, const float* __restrict__ linv_g,
    float* __restrict__ axq, short* __restrict__ Pf, int storeP) {
  __shared__ short kxbuf[2][16 * 512];
  __shared__ short Plds[4][16][32];
  const int tid = threadIdx.x;
  const int w = tid >> 6, l = tid & 63;
  const int row16 = l & 15, grp = l >> 4;
  const int r0 = blockIdx.x * 64 + w * 16;
  const int rtile = blockIdx.x * 4 + w;
  const int jt0 = blockIdx.y * JPB;
  const f32x4 zero4 = {0.f, 0.f, 0.f, 0.f};

  short8 qf[NHEAD];
#pragma unroll
  for (int h = 0; h < NHEAD; ++h)
    qf[h] = *(const short8*)&qb[(((size_t)rtile * 4 + h) << 9) + l * 8];
  float linv[NHEAD][4];
#pragma unroll
  for (int h = 0; h < NHEAD; ++h)
#pragma unroll
    for (int r = 0; r < 4; ++r) linv[h][r] = linv_g[h * NN + r0 + grp * 4 + r];

  f32x4 axa[8];
#pragma unroll
  for (int cg = 0; cg < 8; ++cg) axa[cg] = zero4;

  // chunks 0..7 = K frags, 8..15 = X frags
  for (int c = w; c < 16; c += 4) {
    const short* src = (c < 8) ? kb + (((size_t)jt0 * 8 + c) << 9) + l * 8
                               : xb + (((size_t)jt0 * 8 + (c - 8)) << 9) + l * 8;
    gl_lds16(src, &kxbuf[0][c * 512]);
  }
  __syncthreads();

  for (int j = 0; j < JPB; ++j) {
    int b = j & 1;
    if (j + 1 < JPB) {
      for (int c = w; c < 16; c += 4) {
        const short* src = (c < 8) ? kb + (((size_t)(jt0 + j + 1) * 8 + c) << 9) + l * 8
                                   : xb + (((size_t)(jt0 + j + 1) * 8 + (c - 8)) << 9) + l * 8;
        gl_lds16(src, &kxbuf[b ^ 1][c * 512]);
      }
    }
    const short* kcur = kxbuf[b];
#pragma unroll
    for (int sub = 0; sub < 2; ++sub) {
      float p[4] = {0.f, 0.f, 0.f, 0.f};
#pragma unroll
      for (int h = 0; h < NHEAD; ++h) {
        short8 kf = *(const short8*)&kcur[(h * 2 + sub) * 512 + l * 8];
        f32x4 s = __builtin_amdgcn_mfma_f32_16x16x32_bf16(qf[h], kf, zero4, 0, 0, 0);
#pragma unroll
        for (int r = 0; r < 4; ++r) p[r] += __expf(s[r]) * linv[h][r];
      }
#pragma unroll
      for (int r = 0; r < 4; ++r)
        Plds[w][grp * 4 + r][sub * 16 + row16] = f2b(0.25f * p[r]);
    }
    short8 pa = *(short8*)&Plds[w][row16][grp * 8];
    if (storeP)
      *(short8*)&Pf[((size_t)rtile * 256 + (jt0 + j)) * 512 + l * 8] = pa;
#pragma unroll
    for (int cg = 0; cg < 8; ++cg) {
      short8 xv = *(const short8*)&kcur[(8 + cg) * 512 + l * 8];
      axa[cg] = __builtin_amdgcn_mfma_f32_16x16x32_bf16(pa, xv, axa[cg], 0, 0, 0);
    }
    __syncthreads();
  }
#pragma unroll
  for (int cg = 0; cg < 8; ++cg)
#pragma unroll
    for (int r = 0; r < 4; ++r)
      axq[(size_t)blockIdx.y * NN * TOTD + (size_t)(r0 + grp * 4 + r) * TOTD + cg * 16 + row16] =
          axa[cg][r];
}

// ---------------- K4: ax reduce + r,z gates; v2 fragments --------------------
__global__ void k_rz(const float* __restrict__ axq, const float* __restrict__ hx,
                     const float* __restrict__ Wr, const float* __restrict__ br,
                     const float* __restrict__ Wz, const float* __restrict__ bz,
                     float* __restrict__ ax, float* __restrict__ z,
                     short* __restrict__ v2f) {
  __shared__ float axs[2][TOTD];
  int tid = threadIdx.x;
  int rr = tid >> 7;
  int c2 = tid & 127;
  int n = blockIdx.x * 2 + rr;
  float s = 0.f;
#pragma unroll
  for (int q = 0; q < NCQ; ++q) s += axq[(size_t)q * NN * TOTD + (size_t)n * TOTD + c2];
  axs[rr][c2] = s;
  ax[(size_t)n * TOTD + c2] = s;
  __syncthreads();
  bool isz = c2 >= HIDD;
  int c = c2 & (HIDD - 1);
  const float* W = isz ? Wz : Wr;
  float acc = isz ? bz[c] : br[c];
#pragma unroll
  for (int t = 0; t < TOTD; ++t) acc += axs[rr][t] * W[t * HIDD + c];
  float sg = 1.f / (1.f + __expf(-acc));
  if (isz) {
    z[n * HIDD + c] = sg;
  } else {
    int jt = n >> 5, kk = n & 31, cg = c >> 4;
    int ll = ((kk >> 3) << 4) | (c & 15);
    v2f[(((size_t)jt * 4 + cg) << 9) + (ll << 3) + (kk & 7)] = f2b(sg * hx[n * HIDD + c]);
  }
}

// ---------------- K5a: a2 partials from stored P (pure GEMM) -----------------
__global__ __launch_bounds__(256, 4) void k_pv2P(
    const short* __restrict__ Pf, const short* __restrict__ v2f,
    float* __restrict__ a2q) {
  __shared__ short vbuf[2][4 * 512];
  const int tid = threadIdx.x;
  const int w = tid >> 6, l = tid & 63;
  const int row16 = l & 15, grp = l >> 4;
  const int r0 = blockIdx.x * 64 + w * 16;
  const int rtile = blockIdx.x * 4 + w;
  const int jt0 = blockIdx.y * JPB;

  f32x4 a2a[4];
#pragma unroll
  for (int cg = 0; cg < 4; ++cg) a2a[cg] = {0.f, 0.f, 0.f, 0.f};

  gl_lds16(v2f + (((size_t)jt0 * 4 + w) << 9) + l * 8, &vbuf[0][w * 512]);
  short8 pa = *(const short8*)&Pf[((size_t)rtile * 256 + jt0) * 512 + l * 8];
  __syncthreads();

  for (int j = 0; j < JPB; ++j) {
    int b = j & 1;
    short8 panext = pa;
    if (j + 1 < JPB) {
      gl_lds16(v2f + (((size_t)(jt0 + j + 1) * 4 + w) << 9) + l * 8, &vbuf[b ^ 1][w * 512]);
      panext = *(const short8*)&Pf[((size_t)rtile * 256 + (jt0 + j + 1)) * 512 + l * 8];
    }
#pragma unroll
    for (int cg = 0; cg < 4; ++cg) {
      short8 vv = *(const short8*)&vbuf[b][cg * 512 + l * 8];
      a2a[cg] = __builtin_amdgcn_mfma_f32_16x16x32_bf16(pa, vv, a2a[cg], 0, 0, 0);
    }
    pa = panext;
    __syncthreads();
  }
#pragma unroll
  for (int cg = 0; cg < 4; ++cg)
#pragma unroll
    for (int r = 0; r < 4; ++r)
      a2q[(size_t)blockIdx.y * NN * HIDD + (size_t)(r0 + grp * 4 + r) * HIDD + cg * 16 + row16] =
          a2a[cg][r];
}

// ---------------- K5b: a2 partials recomputing P (fallback, small ws) --------
__global__ __launch_bounds__(256, 4) void k_pv2R(
    const short* __restrict__ qb, const short* __restrict__ kb,
    const short* __restrict__ v2f, const float* __restrict__ linv_g,
    float* __restrict__ a2q) {
  __shared__ short kvbuf[2][12 * 512];
  __shared__ short Plds[4][16][32];
  const int tid = threadIdx.x;
  const int w = tid >> 6, l = tid & 63;
  const int row16 = l & 15, grp = l >> 4;
  const int r0 = blockIdx.x * 64 + w * 16;
  const int rtile = blockIdx.x * 4 + w;
  const int jt0 = blockIdx.y * JPB;
  const f32x4 zero4 = {0.f, 0.f, 0.f, 0.f};

  short8 qf[NHEAD];
#pragma unroll
  for (int h = 0; h < NHEAD; ++h)
    qf[h] = *(const short8*)&qb[(((size_t)rtile * 4 + h) << 9) + l * 8];
  float linv[NHEAD][4];
#pragma unroll
  for (int h = 0; h < NHEAD; ++h)
#pragma unroll
    for (int r = 0; r < 4; ++r) linv[h][r] = linv_g[h * NN + r0 + grp * 4 + r];

  f32x4 a2a[4];
#pragma unroll
  for (int cg = 0; cg < 4; ++cg) a2a[cg] = zero4;

  for (int c = w; c < 12; c += 4) {
    const short* src = (c < 8) ? kb + (((size_t)jt0 * 8 + c) << 9) + l * 8
                               : v2f + (((size_t)jt0 * 4 + (c - 8)) << 9) + l * 8;
    gl_lds16(src, &kvbuf[0][c * 512]);
  }
  __syncthreads();

  for (int j = 0; j < JPB; ++j) {
    int b = j & 1;
    if (j + 1 < JPB) {
      for (int c = w; c < 12; c += 4) {
        const short* src = (c < 8) ? kb + (((size_t)(jt0 + j + 1) * 8 + c) << 9) + l * 8
                                   : v2f + (((size_t)(jt0 + j + 1) * 4 + (c - 8)) << 9) + l * 8;
        gl_lds16(src, &kvbuf[b ^ 1][c * 512]);
      }
    }
    const short* kcur = kvbuf[b];
#pragma unroll
    for (int sub = 0; sub < 2; ++sub) {
      float p[4] = {0.f, 0.f, 0.f, 0.f};
#pragma unroll
      for (int h = 0; h < NHEAD; ++h) {
        short8 kf = *(const short8*)&kcur[(h * 2 + sub) * 512 + l * 8];
        f32x4 s = __builtin_amdgcn_mfma_f32_16x16x32_bf16(qf[h], kf, zero4, 0, 0, 0);
#pragma unroll
        for (int r = 0; r < 4; ++r) p[r] += __expf(s[r]) * linv[h][r];
      }
#pragma unroll
      for (int r = 0; r < 4; ++r)
        Plds[w][grp * 4 + r][sub * 16 + row16] = f2b(0.25f * p[r]);
    }
    short8 pa = *(short8*)&Plds[w][row16][grp * 8];
#pragma unroll
    for (int cg = 0; cg < 4; ++cg) {
      short8 vv = *(const short8*)&kcur[(8 + cg) * 512 + l * 8];
      a2a[cg] = __builtin_amdgcn_mfma_f32_16x16x32_bf16(pa, vv, a2a[cg], 0, 0, 0);
    }
    __syncthreads();
  }
#pragma unroll
  for (int cg = 0; cg < 4; ++cg)
#pragma unroll
    for (int r = 0; r < 4; ++r)
      a2q[(size_t)blockIdx.y * NN * HIDD + (size_t)(r0 + grp * 4 + r) * HIDD + cg * 16 + row16] =
          a2a[cg][r];
}

// ---------------- K6: a2 reduce + GRU epilogue -------------------------------
__global__ __launch_bounds__(256) void k_final(
    const float* __restrict__ a2q, const float* __restrict__ ax,
    const float* __restrict__ hx, const float* __restrict__ Wh,
    const float* __restrict__ bh, const float* __restrict__ z,
    float* __restrict__ out) {
  __shared__ float Whs[TOTD * HIDD];
  __shared__ float a2s[16][HIDD];
  const int tid = threadIdx.x;
  const int r0 = blockIdx.x * 16;

  for (int i = tid; i < TOTD * HIDD; i += 256) Whs[i] = Wh[i];
  for (int i = tid; i < 16 * HIDD; i += 256) {
    int rw = i >> 6, c = i & 63;
    size_t gi = (size_t)(r0 + rw) * HIDD + c;
    float s = 0.f;
#pragma unroll
    for (int q = 0; q < NCQ; ++q) s += a2q[(size_t)q * NN * HIDD + gi];
    a2s[rw][c] = s;
  }
  __syncthreads();
  for (int o = tid; o < 16 * HIDD; o += 256) {
    int rw = o >> 6, c = o & 63;
    const float* axrow = &ax[(size_t)(r0 + rw) * TOTD];
    float acc = bh[c];
#pragma unroll
    for (int t = 0; t < 64; ++t) acc += axrow[t] * Whs[t * HIDD + c];
#pragma unroll
    for (int t = 0; t < 64; ++t) acc += a2s[rw][t] * Whs[(64 + t) * HIDD + c];
    float hval = tanhf(acc);
    size_t gi = (size_t)(r0 + rw) * HIDD + c;
    float zz = z[gi];
    out[gi] = zz * hx[gi] + (1.f - zz) * hval;
  }
}

extern "C" void kernel_launch(void* const* d_in, const int* in_sizes, int n_in,
                              void* d_out, int out_size, void* d_ws, size_t ws_size,
                              hipStream_t stream) {
  const float* in = (const float*)d_in[0];
  const float* hx = (const float*)d_in[1];
  const float* Wq = (const float*)d_in[2];
  const float* Wk = (const float*)d_in[3];
  const float* Wr = (const float*)d_in[4];
  const float* br = (const float*)d_in[5];
  const float* Wz = (const float*)d_in[6];
  const float* bz = (const float*)d_in[7];
  const float* Wh = (const float*)d_in[8];
  const float* bh = (const float*)d_in[9];

  const size_t MB = 1ull << 20;
  char* ws = (char*)d_ws;
  short* qb    = (short*)(ws + 0 * MB);          // 2 MB
  short* kb    = (short*)(ws + 2 * MB);          // 2 MB
  short* xb    = (short*)(ws + 4 * MB);          // 2 MB
  float* linv  = (float*)(ws + 6 * MB);          // 128 KB
  float* lpart = (float*)(ws + 6 * MB + 262144); // 1 MB
  float* ax    = (float*)(ws + 8 * MB);          // 4 MB
  float* z     = (float*)(ws + 12 * MB);         // 2 MB
  short* v2f   = (short*)(ws + 14 * MB);         // 1 MB
  float* axq   = (float*)(ws + 16 * MB);         // 32 MB
  float* a2q   = (float*)(ws + 48 * MB);         // 16 MB
  short* Pf    = (short*)(ws + 64 * MB);         // 128 MB (optional)
  float* out   = (float*)d_out;
  int useP = (ws_size >= 192 * MB) ? 1 : 0;

  k_build_xfrag<<<dim3((NN * TOTD) / 256), dim3(256), 0, stream>>>(in, hx, xb);
  k_qk<<<dim3(NN), dim3(256), 0, stream>>>(in, hx, Wq, Wk, qb, kb);
  k_denom<<<dim3(NN / 64, NCQ), dim3(256), 0, stream>>>(qb, kb, lpart);
  k_linv<<<dim3((NHEAD * NN) / 256), dim3(256), 0, stream>>>(lpart, linv);
  k_pv1<<<dim3(NN / 64, NCQ), dim3(256), 0, stream>>>(qb, kb, xb, linv, axq, Pf, useP);
  k_rz<<<dim3(NN / 2), dim3(256), 0, stream>>>(axq, hx, Wr, br, Wz, bz, ax, z, v2f);
  if (useP)
    k_pv2P<<<dim3(NN / 64, NCQ), dim3(256), 0, stream>>>(Pf, v2f, a2q);
  else
    k_pv2R<<<dim3(NN / 64, NCQ), dim3(256), 0, stream>>>(qb, kb, v2f, linv, a2q);
  k_final<<<dim3(NN / 16), dim3(256), 0, stream>>>(a2q, ax, hx, Wh, bh, z, out);
}